// Round 9
// baseline (7310.936 us; speedup 1.0000x reference)
//
#include <hip/hip_runtime.h>
#include <cstdint>
#include <cstddef>

// ---------------------------------------------------------------------------
// RLSTM: B=32, T=1024, F=256, H=256.
// Identities: a_rec = a_cur[idx]; gate chunk 4 unused (o_t = i_t); x@W is
// recurrence-free (phase A). Phase B: 64 persistent WGs, each owns 4 h-cols
// (12 gate cols). R9: LDS-instruction diet + pipelined gather --
//   * h@U: 2b x 2jc x k-half blocking: 384 ds_read_b128 (was 576). k-split
//     association (red0+red1+xw) is exactly R1's, which passed absmax 0.0.
//   * Split sync: cntA (wgs 0-31) / cntB (32-63). Wave 0 polls cntA, gathers
//     lower 16KB solo, releases LDS flag fA; khalf0 threads compute k<128
//     while wave 0 polls cntB + gathers upper -> fB. No barriers A/B.
//   * Gate from wave 0's in-register h (fp64, order-free) -- no hL reads.
//   * Direct owner publish (128 coalesced dword sc0sc1 stores), barrier, one
//     atomicAdd. hpub + barrier F gone. 3 barriers/step (was 4).
// P-mix/LSTM chains byte-identical to R8.
// ---------------------------------------------------------------------------

#define T_STEPS 1024
#define BSZ 32
#define FDIM 256
#define HDIM 256
#define G3W 384          // per-WG gate cols x batch (12*32) flat row
#define KWG 64           // phase-B workgroups (co-resident on 256 CUs)
#define HS 4             // h-cols per WG
#define JC 12            // gate cols per WG (3 chunks x HS)
#define HPAD 260         // LDS row pad
#define OMEGA 32
#define HSLICE 8192      // floats per hbank step slice (32*256)

static const size_t AXC_BYTES = (size_t)KWG * T_STEPS * G3W * sizeof(float);      // 96 MiB
static const size_t HB_BYTES  = (size_t)(T_STEPS + 1) * HSLICE * sizeof(float);   // 32 MiB
static const size_t GX_BYTES  = (size_t)T_STEPS * sizeof(double);

// ------------------------------ Phase A ------------------------------------
__global__ __launch_bounds__(256) void phaseA(const float* __restrict__ x,
                                              const float* __restrict__ W,
                                              const float* __restrict__ W_r,
                                              const float* __restrict__ P_r,
                                              float* __restrict__ AXc,
                                              double* __restrict__ gx) {
  const int t = blockIdx.x;
  const int tid = threadIdx.x;
  __shared__ __align__(16) float xs[BSZ][HPAD];
  __shared__ double sred[BSZ];

  for (int i = tid; i < BSZ * FDIM / 4; i += 256) {
    const int b = (i * 4) >> 8;
    const int k = (i * 4) & 255;
    *(float4*)&xs[b][k] = *(const float4*)&x[((size_t)b * T_STEPS + t) * FDIM + k];
  }
  __syncthreads();

  for (int pass = 0; pass < 3; ++pass) {
    const int j = pass * 256 + tid;           // gate col in [0,768)
    float acc[BSZ];
#pragma unroll
    for (int b = 0; b < BSZ; ++b) acc[b] = 0.f;
    for (int k0 = 0; k0 < FDIM; k0 += 4) {
      const float w0 = W[(size_t)(k0 + 0) * 1024 + j];
      const float w1 = W[(size_t)(k0 + 1) * 1024 + j];
      const float w2 = W[(size_t)(k0 + 2) * 1024 + j];
      const float w3 = W[(size_t)(k0 + 3) * 1024 + j];
#pragma unroll
      for (int b = 0; b < BSZ; ++b) {
        const float4 xv = *(const float4*)&xs[b][k0];  // LDS broadcast
        acc[b] = fmaf(xv.x, w0, acc[b]);
        acc[b] = fmaf(xv.y, w1, acc[b]);
        acc[b] = fmaf(xv.z, w2, acc[b]);
        acc[b] = fmaf(xv.w, w3, acc[b]);
      }
    }
    // AXc[wg][t][b*12 + slot], wg = (j%256)/4, slot = (j/256)*4 + j%4
    const int wgj = (j >> 2) & 63;
    const int slot = ((j >> 8) << 2) | (j & 3);
    float* dst = AXc + ((size_t)wgj * T_STEPS + t) * G3W + slot;
    for (int b = 0; b < BSZ; ++b) dst[b * 12] = acc[b];
  }

  if (tid < BSZ) {
    double s = 0.0;
    for (int k = 0; k < FDIM; k += 4) {
      const float4 xv = *(const float4*)&xs[tid][k];
      const float4 wv = *(const float4*)&W_r[k];
      s = fma((double)xv.x, (double)wv.x, s);
      s = fma((double)xv.y, (double)wv.y, s);
      s = fma((double)xv.z, (double)wv.z, s);
      s = fma((double)xv.w, (double)wv.w, s);
    }
    sred[tid] = s;
  }
  __syncthreads();
  if (tid == 0) {
    double g = 0.0;
    for (int b = 0; b < BSZ; ++b) g = fma((double)P_r[b], sred[b], g);
    gx[t] = g;
  }
}

// ------------------------------ Phase B ------------------------------------
__global__ __launch_bounds__(256) void phaseB(const float* __restrict__ U,
                                              const float* __restrict__ P,
                                              const float* __restrict__ B_bias,
                                              const float* __restrict__ P_r,
                                              const float* __restrict__ U_r,
                                              float* __restrict__ AXc,
                                              float* __restrict__ hbank,
                                              const double* __restrict__ gx,
                                              unsigned int* __restrict__ cnt) {
  const int wg = blockIdx.x;
  const int tid = threadIdx.x;
  const int lane = tid & 63;

  __shared__ __align__(16) float ULt[JC][HPAD];   // U cols for this WG, k-major
  __shared__ __align__(16) float hL[BSZ][HPAD];   // h_{t-1}, full
  __shared__ __align__(16) float PL[BSZ][64];
  __shared__ __align__(16) float acs[JC][36];     // a_cur slice [jc][b]
  __shared__ __align__(16) float ars[JC][36];     // a_rec slice
  __shared__ __align__(16) float red1[BSZ][JC];   // k-upper partials [b][jc]
  __shared__ __align__(16) float UrL[FDIM];
  __shared__ float PrL[BSZ];
  __shared__ float biasL[JC];
  __shared__ int fA, fB;                          // LDS step flags

  for (int i = tid; i < JC * HDIM; i += 256) {
    const int jc = i >> 8, k = i & 255;
    const int col = (jc >> 2) * HDIM + wg * HS + (jc & 3);
    ULt[jc][k] = U[(size_t)k * 1024 + col];
  }
  for (int i = tid; i < BSZ * 64; i += 256) PL[i >> 6][i & 63] = P[i];
  if (tid < FDIM) UrL[tid] = U_r[tid];
  if (tid < BSZ) PrL[tid] = P_r[tid];
  if (tid < JC) biasL[tid] = B_bias[(tid >> 2) * HDIM + wg * HS + (tid & 3)];
  if (tid == 0) { fA = 0; fB = 0; }

  // h@U map: threads 64..255, u in [0,192): khalf = u/96 (k-range),
  // r = u%96: jcp = r%6, bA = r/6; outputs (bA,bB=bA+16) x (jc0,jc1).
  const int u = (tid >= 64) ? (tid - 64) : 0;
  const int khalf = u / 96;
  const int rmap = u % 96;
  const int jcp = rmap % 6, bA = rmap / 6;
  const int jc0 = 2 * jcp, jc1 = jc0 + 1;
  const int bB = bA + 16;
  const int kb = khalf * 128;

  const int ob = tid >> 2, ohc = tid & 3;  // owner mapping (tid<128)

  unsigned int* cntA = cnt;
  unsigned int* cntB = cnt + 32;           // separate cache line

  float* __restrict__ AXwg = AXc + (size_t)wg * T_STEPS * G3W;

  float creg = 0.f;  // c state: threads tid<128 own (b=tid>>2, hc=tid&3)
  __syncthreads();

  for (int t = 0; t < T_STEPS; ++t) {
    // ---- prefetch XW (combine threads 64..159 need 4 values) -------------
    float2 xwA = {0.f, 0.f}, xwB = {0.f, 0.f};
    size_t aA = 0, aB = 0;
    if (tid >= 64 && tid < 160) {
      aA = (size_t)t * G3W + bA * JC + jc0;
      aB = (size_t)t * G3W + bB * JC + jc0;
      xwA = *(const float2*)&AXwg[aA];
      xwB = *(const float2*)&AXwg[aB];
    }
    double gxt = 0.0;
    if (tid == 0) gxt = gx[t];

    float s00 = 0.f, s01 = 0.f, s10 = 0.f, s11 = 0.f;  // h@U partials

    if (tid < 64) {
      // ================= wave 0: poll / gather / flags / gate =============
      double sg = 0.0;
      const uint64_t hsrc = (uint64_t)(hbank + (size_t)t * HSLICE);
      const int row = lane & 31;
#pragma unroll
      for (int half = 0; half < 2; ++half) {
        if (t > 0) {
          unsigned int* c = (half == 0) ? cntA : cntB;
          const unsigned tgt = 32u * (unsigned)t;
          int guard = 0;
          while (__hip_atomic_load(c, __ATOMIC_RELAXED,
                                   __HIP_MEMORY_SCOPE_AGENT) < tgt) {
            if (++guard > (1 << 20)) break;  // hang guard
          }
          asm volatile("" ::: "memory");
        }
        // gather 16KB: 16 coalesced dwordx4 bypass loads, ONE waitcnt
        const uint64_t b0 = hsrc + (uint64_t)lane * 16u + (uint64_t)half * 16384u;
        const uint64_t b1 = b0 + 4096u;
        const uint64_t b2 = b0 + 8192u;
        const uint64_t b3 = b0 + 12288u;
        float4 g0, g1, g2, g3, g4, g5, g6, g7, g8, g9, g10, g11, g12, g13, g14, g15;
        asm volatile(
            "global_load_dwordx4 %0, %16, off sc0 sc1\n\t"
            "global_load_dwordx4 %1, %16, off offset:1024 sc0 sc1\n\t"
            "global_load_dwordx4 %2, %16, off offset:2048 sc0 sc1\n\t"
            "global_load_dwordx4 %3, %16, off offset:3072 sc0 sc1\n\t"
            "global_load_dwordx4 %4, %17, off sc0 sc1\n\t"
            "global_load_dwordx4 %5, %17, off offset:1024 sc0 sc1\n\t"
            "global_load_dwordx4 %6, %17, off offset:2048 sc0 sc1\n\t"
            "global_load_dwordx4 %7, %17, off offset:3072 sc0 sc1\n\t"
            "global_load_dwordx4 %8, %18, off sc0 sc1\n\t"
            "global_load_dwordx4 %9, %18, off offset:1024 sc0 sc1\n\t"
            "global_load_dwordx4 %10, %18, off offset:2048 sc0 sc1\n\t"
            "global_load_dwordx4 %11, %18, off offset:3072 sc0 sc1\n\t"
            "global_load_dwordx4 %12, %19, off sc0 sc1\n\t"
            "global_load_dwordx4 %13, %19, off offset:1024 sc0 sc1\n\t"
            "global_load_dwordx4 %14, %19, off offset:2048 sc0 sc1\n\t"
            "global_load_dwordx4 %15, %19, off offset:3072 sc0 sc1\n\t"
            "s_waitcnt vmcnt(0)"
            : "=&v"(g0), "=&v"(g1), "=&v"(g2), "=&v"(g3),
              "=&v"(g4), "=&v"(g5), "=&v"(g6), "=&v"(g7),
              "=&v"(g8), "=&v"(g9), "=&v"(g10), "=&v"(g11),
              "=&v"(g12), "=&v"(g13), "=&v"(g14), "=&v"(g15)
            : "v"(b0), "v"(b1), "v"(b2), "v"(b3)
            : "memory");
        // scatter to hL: load jj covers dwords lane*4 + jj*256 (+half*4096)
        // -> hL[lane&31][4*(lane>>5) + 128*half + 8*jj]
        const int cb = 4 * (lane >> 5) + 128 * half;
        float4 gr[16] = {g0, g1, g2, g3, g4, g5, g6, g7,
                         g8, g9, g10, g11, g12, g13, g14, g15};
#pragma unroll
        for (int jj = 0; jj < 16; ++jj) {
          *(float4*)&hL[row][cb + 8 * jj] = gr[jj];
        }
        // gate partial from registers (fp64 -> order-free)
        if (t >= OMEGA) {
#pragma unroll
          for (int jj = 0; jj < 16; ++jj) {
            const float4 hv = gr[jj];
            const float4 uv = *(const float4*)&UrL[cb + 8 * jj];
            sg = fma((double)hv.x, (double)uv.x, sg);
            sg = fma((double)hv.y, (double)uv.y, sg);
            sg = fma((double)hv.z, (double)uv.z, sg);
            sg = fma((double)hv.w, (double)uv.w, sg);
          }
        }
        __builtin_amdgcn_s_waitcnt(0);  // drain ds_writes before flag
        if (lane == 0) {
          __hip_atomic_store((half == 0) ? &fA : &fB, t + 1,
                             __ATOMIC_RELAXED, __HIP_MEMORY_SCOPE_WORKGROUP);
        }
      }
      if (t >= OMEGA) {
        // lanes l and l^32 hold complementary halves of row (l&31)
        sg += __shfl_xor(sg, 32, 64);
        double v = (double)PrL[row] * sg;
        v += __shfl_xor(v, 16, 64);
        v += __shfl_xor(v, 8, 64);
        v += __shfl_xor(v, 4, 64);
        v += __shfl_xor(v, 2, 64);
        v += __shfl_xor(v, 1, 64);
        int idx = 0;
        if (tid == 0) {
          const double g = gxt + v;
          const double gate = 1.0 / (1.0 + exp(-g));
          idx = (int)rint((double)t * gate);  // ties-to-even == jnp.round
          if (idx > t - 1) idx = t - 1;
          if (idx < 0) idx = 0;
        }
        idx = __shfl(idx, 0, 64);
        // a_rec = a_cur[idx]: contiguous 1.5KB block in our own AXc region
        const float* __restrict__ src = AXwg + (size_t)idx * G3W;
        float av[6];
#pragma unroll
        for (int j = 0; j < 6; ++j) av[j] = src[lane + j * 64];
#pragma unroll
        for (int j = 0; j < 6; ++j) {
          const int f = lane + j * 64;
          ars[f % JC][f / JC] = av[j];
        }
      }
    } else {
      // ============ waves 1-3: spin needed flag, h@U over k-half ==========
      {
        int guard = 0;
        int* fp = (khalf == 0) ? &fA : &fB;
        while (__hip_atomic_load(fp, __ATOMIC_RELAXED,
                                 __HIP_MEMORY_SCOPE_WORKGROUP) < t + 1) {
          if (++guard > (1 << 20)) break;  // hang guard
        }
        asm volatile("" ::: "memory");
      }
      for (int k = kb; k < kb + 128; k += 4) {
        const float4 u0 = *(const float4*)&ULt[jc0][k];
        const float4 u1 = *(const float4*)&ULt[jc1][k];
        const float4 h0 = *(const float4*)&hL[bA][k];
        const float4 h1 = *(const float4*)&hL[bB][k];
        s00 = fmaf(h0.x, u0.x, s00); s00 = fmaf(h0.y, u0.y, s00);
        s00 = fmaf(h0.z, u0.z, s00); s00 = fmaf(h0.w, u0.w, s00);
        s01 = fmaf(h0.x, u1.x, s01); s01 = fmaf(h0.y, u1.y, s01);
        s01 = fmaf(h0.z, u1.z, s01); s01 = fmaf(h0.w, u1.w, s01);
        s10 = fmaf(h1.x, u0.x, s10); s10 = fmaf(h1.y, u0.y, s10);
        s10 = fmaf(h1.z, u0.z, s10); s10 = fmaf(h1.w, u0.w, s10);
        s11 = fmaf(h1.x, u1.x, s11); s11 = fmaf(h1.y, u1.y, s11);
        s11 = fmaf(h1.z, u1.z, s11); s11 = fmaf(h1.w, u1.w, s11);
      }
      if (khalf == 1) {  // store k-upper partials
        *(float2*)&red1[bA][jc0] = make_float2(s00, s01);
        *(float2*)&red1[bB][jc0] = make_float2(s10, s11);
      }
    }
    __syncthreads();  // C1: partials + ars complete

    // ---- combine (khalf0 threads): a_cur = red0 + red1 + xw (R1 assoc) ---
    if (tid >= 64 && tid < 160) {
      const float2 rA = *(const float2*)&red1[bA][jc0];
      const float2 rB = *(const float2*)&red1[bB][jc0];
      const float v00 = s00 + rA.x + xwA.x;
      const float v01 = s01 + rA.y + xwA.y;
      const float v10 = s10 + rB.x + xwB.x;
      const float v11 = s11 + rB.y + xwB.y;
      *(float2*)&AXwg[aA] = make_float2(v00, v01);  // bank for future a_rec
      *(float2*)&AXwg[aB] = make_float2(v10, v11);
      acs[jc0][bA] = v00;  acs[jc1][bA] = v01;
      acs[jc0][bB] = v10;  acs[jc1][bB] = v11;
      if (t < OMEGA) {  // use_self: a_rec == a_cur
        ars[jc0][bA] = v00;  ars[jc1][bA] = v01;
        ars[jc0][bB] = v10;  ars[jc1][bB] = v11;
      }
    }
    __syncthreads();  // C2: acs/ars complete

    // ---- owners: gates = P @ [a_cur; a_rec] + bias, LSTM, direct publish -
    if (tid < BSZ * HS) {
      float gi = biasL[ohc];
      float gf = biasL[4 + ohc];
      float gg = biasL[8 + ohc];
#pragma unroll
      for (int b4 = 0; b4 < BSZ; b4 += 4) {
        const float4 pv = *(const float4*)&PL[ob][b4];
        const float4 ai = *(const float4*)&acs[ohc][b4];
        const float4 af = *(const float4*)&acs[4 + ohc][b4];
        const float4 ag = *(const float4*)&acs[8 + ohc][b4];
        gi = fmaf(pv.x, ai.x, gi); gi = fmaf(pv.y, ai.y, gi);
        gi = fmaf(pv.z, ai.z, gi); gi = fmaf(pv.w, ai.w, gi);
        gf = fmaf(pv.x, af.x, gf); gf = fmaf(pv.y, af.y, gf);
        gf = fmaf(pv.z, af.z, gf); gf = fmaf(pv.w, af.w, gf);
        gg = fmaf(pv.x, ag.x, gg); gg = fmaf(pv.y, ag.y, gg);
        gg = fmaf(pv.z, ag.z, gg); gg = fmaf(pv.w, ag.w, gg);
      }
#pragma unroll
      for (int b4 = 0; b4 < BSZ; b4 += 4) {
        const float4 pv = *(const float4*)&PL[ob][BSZ + b4];
        const float4 ai = *(const float4*)&ars[ohc][b4];
        const float4 af = *(const float4*)&ars[4 + ohc][b4];
        const float4 ag = *(const float4*)&ars[8 + ohc][b4];
        gi = fmaf(pv.x, ai.x, gi); gi = fmaf(pv.y, ai.y, gi);
        gi = fmaf(pv.z, ai.z, gi); gi = fmaf(pv.w, ai.w, gi);
        gf = fmaf(pv.x, af.x, gf); gf = fmaf(pv.y, af.y, gf);
        gf = fmaf(pv.z, af.z, gf); gf = fmaf(pv.w, af.w, gf);
        gg = fmaf(pv.x, ag.x, gg); gg = fmaf(pv.y, ag.y, gg);
        gg = fmaf(pv.z, ag.z, gg); gg = fmaf(pv.w, ag.w, gg);
      }
      const float iv = 1.f / (1.f + expf(-gi));
      const float fv = 1.f / (1.f + expf(-gf));
      const float gv = tanhf(gg);
      creg = fmaf(fv, creg, iv * gv);
      const float hv = iv * tanhf(creg);  // o_t = i_t (faithful to source)
      // direct publish: [wg][b][c] flat idx == tid (b=tid>>2, hc=tid&3)
      const uint64_t daddr =
          (uint64_t)(hbank + (size_t)(t + 1) * HSLICE + (size_t)wg * (BSZ * HS)) +
          (uint64_t)tid * 4u;
      asm volatile(
          "global_store_dword %0, %1, off sc0 sc1\n\t"
          "s_waitcnt vmcnt(0)"
          :: "v"(daddr), "v"(hv)
          : "memory");
    }
    __syncthreads();  // D: all publish stores drained
    if (tid == 0) {
      __hip_atomic_fetch_add((wg < 32) ? cntA : cntB, 1u, __ATOMIC_RELAXED,
                             __HIP_MEMORY_SCOPE_AGENT);
    }
  }
}

// ------------------------------ Output -------------------------------------
__global__ void outK(const float* __restrict__ hbank, const float* __restrict__ W_out,
                     const float* __restrict__ b_out, float* __restrict__ out) {
  const int b = threadIdx.x;
  if (b < BSZ) {
    const float* h = hbank + (size_t)T_STEPS * HSLICE;  // [wg][b][c]
    float s = 0.f;
    for (int wg = 0; wg < KWG; ++wg) {
      const float4 hv = *(const float4*)&h[wg * (BSZ * HS) + b * HS];
      const float4 wv = *(const float4*)&W_out[wg * HS];
      s = fmaf(hv.x, wv.x, s); s = fmaf(hv.y, wv.y, s);
      s = fmaf(hv.z, wv.z, s); s = fmaf(hv.w, wv.w, s);
    }
    out[b] = s + b_out[0];
  }
}

// ------------------------------ Launch -------------------------------------
extern "C" void kernel_launch(void* const* d_in, const int* in_sizes, int n_in,
                              void* d_out, int out_size, void* d_ws, size_t ws_size,
                              hipStream_t stream) {
  const float* x      = (const float*)d_in[0];
  const float* W      = (const float*)d_in[1];
  const float* U      = (const float*)d_in[2];
  const float* P      = (const float*)d_in[3];
  const float* B_bias = (const float*)d_in[4];
  const float* W_r    = (const float*)d_in[5];
  const float* P_r    = (const float*)d_in[6];
  const float* U_r    = (const float*)d_in[7];
  const float* W_out  = (const float*)d_in[8];
  const float* b_out  = (const float*)d_in[9];

  char* ws = (char*)d_ws;
  float*    AXc   = (float*)ws;
  float*    hbank = (float*)(ws + AXC_BYTES);
  double*   gx    = (double*)(ws + AXC_BYTES + HB_BYTES);
  unsigned* cnt   = (unsigned*)(ws + AXC_BYTES + HB_BYTES + GX_BYTES);

  hipMemsetAsync(hbank, 0, (size_t)HSLICE * sizeof(float), stream);  // h0 = 0
  hipMemsetAsync(cnt, 0, 256, stream);                               // counters

  phaseA<<<T_STEPS, 256, 0, stream>>>(x, W, W_r, P_r, AXc, gx);
  phaseB<<<KWG, 256, 0, stream>>>(U, P, B_bias, P_r, U_r, AXc, hbank, gx, cnt);
  outK<<<1, 64, 0, stream>>>(hbank, W_out, b_out, (float*)d_out);
}

// Round 10
// 5254.258 us; speedup vs baseline: 1.3914x; 1.3914x over previous
//
#include <hip/hip_runtime.h>
#include <cstdint>
#include <cstddef>

// ---------------------------------------------------------------------------
// RLSTM: B=32, T=1024, F=256, H=256.
// Identities: a_rec = a_cur[idx]; gate chunk 4 unused (o_t = i_t); x@W is
// recurrence-free (phase A). Phase B: 64 persistent WGs, each owns 4 h-cols
// (12 gate cols). R10 = R8 skeleton (parallel 256-thread gather, barrier
// sync, wave-0 poll -- R9's wave-0 solo gather serialized 2 RTs and
// regressed) + the good parts of R9:
//   * h@U 2b x 2jc x k-half map: 384 ds_read_b128 (was 576); combine
//     red0+red1+xw is the R1/R9-proven association (absmax 0.0).
//   * direct owner publish (128 coalesced dword sc0sc1; no hpub stage).
//   * 8-way striped counters: 8 adds/line/step, poll reads 8 lines at once.
// P-mix/LSTM chains byte-identical to R8.
// ---------------------------------------------------------------------------

#define T_STEPS 1024
#define BSZ 32
#define FDIM 256
#define HDIM 256
#define G3W 384          // per-WG gate cols x batch (12*32) flat row
#define KWG 64           // phase-B workgroups (co-resident on 256 CUs)
#define HS 4             // h-cols per WG
#define JC 12            // gate cols per WG (3 chunks x HS)
#define HPAD 260         // LDS row pad
#define OMEGA 32
#define HSLICE 8192      // floats per hbank step slice (32*256)

static const size_t AXC_BYTES = (size_t)KWG * T_STEPS * G3W * sizeof(float);      // 96 MiB
static const size_t HB_BYTES  = (size_t)(T_STEPS + 1) * HSLICE * sizeof(float);   // 32 MiB
static const size_t GX_BYTES  = (size_t)T_STEPS * sizeof(double);

// ------------------------------ Phase A ------------------------------------
__global__ __launch_bounds__(256) void phaseA(const float* __restrict__ x,
                                              const float* __restrict__ W,
                                              const float* __restrict__ W_r,
                                              const float* __restrict__ P_r,
                                              float* __restrict__ AXc,
                                              double* __restrict__ gx) {
  const int t = blockIdx.x;
  const int tid = threadIdx.x;
  __shared__ __align__(16) float xs[BSZ][HPAD];
  __shared__ double sred[BSZ];

  for (int i = tid; i < BSZ * FDIM / 4; i += 256) {
    const int b = (i * 4) >> 8;
    const int k = (i * 4) & 255;
    *(float4*)&xs[b][k] = *(const float4*)&x[((size_t)b * T_STEPS + t) * FDIM + k];
  }
  __syncthreads();

  for (int pass = 0; pass < 3; ++pass) {
    const int j = pass * 256 + tid;           // gate col in [0,768)
    float acc[BSZ];
#pragma unroll
    for (int b = 0; b < BSZ; ++b) acc[b] = 0.f;
    for (int k0 = 0; k0 < FDIM; k0 += 4) {
      const float w0 = W[(size_t)(k0 + 0) * 1024 + j];
      const float w1 = W[(size_t)(k0 + 1) * 1024 + j];
      const float w2 = W[(size_t)(k0 + 2) * 1024 + j];
      const float w3 = W[(size_t)(k0 + 3) * 1024 + j];
#pragma unroll
      for (int b = 0; b < BSZ; ++b) {
        const float4 xv = *(const float4*)&xs[b][k0];  // LDS broadcast
        acc[b] = fmaf(xv.x, w0, acc[b]);
        acc[b] = fmaf(xv.y, w1, acc[b]);
        acc[b] = fmaf(xv.z, w2, acc[b]);
        acc[b] = fmaf(xv.w, w3, acc[b]);
      }
    }
    // AXc[wg][t][b*12 + slot], wg = (j%256)/4, slot = (j/256)*4 + j%4
    const int wgj = (j >> 2) & 63;
    const int slot = ((j >> 8) << 2) | (j & 3);
    float* dst = AXc + ((size_t)wgj * T_STEPS + t) * G3W + slot;
    for (int b = 0; b < BSZ; ++b) dst[b * 12] = acc[b];
  }

  if (tid < BSZ) {
    double s = 0.0;
    for (int k = 0; k < FDIM; k += 4) {
      const float4 xv = *(const float4*)&xs[tid][k];
      const float4 wv = *(const float4*)&W_r[k];
      s = fma((double)xv.x, (double)wv.x, s);
      s = fma((double)xv.y, (double)wv.y, s);
      s = fma((double)xv.z, (double)wv.z, s);
      s = fma((double)xv.w, (double)wv.w, s);
    }
    sred[tid] = s;
  }
  __syncthreads();
  if (tid == 0) {
    double g = 0.0;
    for (int b = 0; b < BSZ; ++b) g = fma((double)P_r[b], sred[b], g);
    gx[t] = g;
  }
}

// ------------------------------ Phase B ------------------------------------
__global__ __launch_bounds__(256) void phaseB(const float* __restrict__ U,
                                              const float* __restrict__ P,
                                              const float* __restrict__ B_bias,
                                              const float* __restrict__ P_r,
                                              const float* __restrict__ U_r,
                                              float* __restrict__ AXc,
                                              float* __restrict__ hbank,
                                              const double* __restrict__ gx,
                                              unsigned int* __restrict__ cnt) {
  const int wg = blockIdx.x;
  const int tid = threadIdx.x;
  const int lane = tid & 63;

  __shared__ __align__(16) float ULt[JC][HPAD];   // U cols for this WG, k-major
  __shared__ __align__(16) float hL[BSZ][HPAD];   // h_{t-1}, full
  __shared__ __align__(16) float PL[BSZ][64];
  __shared__ __align__(16) float acs[JC][36];     // a_cur slice [jc][b]
  __shared__ __align__(16) float ars[JC][36];     // a_rec slice
  __shared__ __align__(16) float red1[BSZ][JC];   // k-upper partials [b][jc]
  __shared__ __align__(16) float UrL[FDIM];
  __shared__ float PrL[BSZ];
  __shared__ float biasL[JC];

  for (int i = tid; i < JC * HDIM; i += 256) {
    const int jc = i >> 8, k = i & 255;
    const int col = (jc >> 2) * HDIM + wg * HS + (jc & 3);
    ULt[jc][k] = U[(size_t)k * 1024 + col];
  }
  for (int i = tid; i < BSZ * 64; i += 256) PL[i >> 6][i & 63] = P[i];
  if (tid < FDIM) UrL[tid] = U_r[tid];
  if (tid < BSZ) PrL[tid] = P_r[tid];
  if (tid < JC) biasL[tid] = B_bias[(tid >> 2) * HDIM + wg * HS + (tid & 3)];

  // h@U map: threads 64..255, u in [0,192): khalf = u/96 (k-range),
  // r = u%96: jcp = r%6, bA = r/6; outputs (bA,bB=bA+16) x (jc0,jc1).
  const int u = (tid >= 64) ? (tid - 64) : 0;
  const int khalf = u / 96;
  const int rmap = u % 96;
  const int jcp = rmap % 6, bA = rmap / 6;
  const int jc0 = 2 * jcp, jc1 = jc0 + 1;
  const int bB = bA + 16;
  const int kb = khalf * 128;

  const int ob = tid >> 2, ohc = tid & 3;  // owner mapping (tid<128)
  // gather scatter mapping (coalesced): instr j covers dwords
  // d = tid*4 + j*1024 -> hL[tid&31][4*(tid>>5) + 32*j]
  const int grow = tid & 31;
  const int gc0 = (tid >> 5) * 4;

  float* __restrict__ AXwg = AXc + (size_t)wg * T_STEPS * G3W;

  float creg = 0.f;  // c state: threads tid<128 own (b=tid>>2, hc=tid&3)
  __syncthreads();

  for (int t = 0; t < T_STEPS; ++t) {
    // ---- prefetch XW (combine threads 64..159 need 4 values) -------------
    float2 xwA = {0.f, 0.f}, xwB = {0.f, 0.f};
    size_t aA = 0, aB = 0;
    if (tid >= 64 && tid < 160) {
      aA = (size_t)t * G3W + bA * JC + jc0;
      aB = (size_t)t * G3W + bB * JC + jc0;
      xwA = *(const float2*)&AXwg[aA];
      xwB = *(const float2*)&AXwg[aB];
    }
    double gxt = 0.0;
    if (tid == 0) gxt = gx[t];

    // ---- wave 0 polls 8 striped counters; others park at barrier A -------
    if (t > 0) {
      if (tid < 64) {
        const unsigned tgt = 8u * (unsigned)t;
        int guard = 0;
        for (;;) {
          unsigned v = tgt;
          if (lane < 8) {
            v = __hip_atomic_load(&cnt[lane * 32], __ATOMIC_RELAXED,
                                  __HIP_MEMORY_SCOPE_AGENT);
          }
          if (__all((int)(v >= tgt))) break;
          if (++guard > (1 << 20)) break;  // hang guard (never trips normally)
        }
      }
      __syncthreads();  // A
      asm volatile("" ::: "memory");  // no hoisting loads above the poll
    }

    // ---- gather h_{t-1}: 8 coalesced dwordx4 bypass loads, ONE waitcnt ---
    {
      const uint64_t base =
          (uint64_t)(hbank + (size_t)t * HSLICE) + (uint64_t)tid * 16u;
      const uint64_t a0 = base;
      const uint64_t a1 = base + 4096u;
      const uint64_t a2 = base + 8192u;
      const uint64_t a3 = base + 12288u;
      const uint64_t a4 = base + 16384u;
      const uint64_t a5 = base + 20480u;
      const uint64_t a6 = base + 24576u;
      const uint64_t a7 = base + 28672u;
      float4 r0, r1, r2, r3, r4, r5, r6, r7;
      asm volatile(
          "global_load_dwordx4 %0, %8, off sc0 sc1\n\t"
          "global_load_dwordx4 %1, %9, off sc0 sc1\n\t"
          "global_load_dwordx4 %2, %10, off sc0 sc1\n\t"
          "global_load_dwordx4 %3, %11, off sc0 sc1\n\t"
          "global_load_dwordx4 %4, %12, off sc0 sc1\n\t"
          "global_load_dwordx4 %5, %13, off sc0 sc1\n\t"
          "global_load_dwordx4 %6, %14, off sc0 sc1\n\t"
          "global_load_dwordx4 %7, %15, off sc0 sc1\n\t"
          "s_waitcnt vmcnt(0)"
          : "=&v"(r0), "=&v"(r1), "=&v"(r2), "=&v"(r3),
            "=&v"(r4), "=&v"(r5), "=&v"(r6), "=&v"(r7)
          : "v"(a0), "v"(a1), "v"(a2), "v"(a3),
            "v"(a4), "v"(a5), "v"(a6), "v"(a7)
          : "memory");
      *(float4*)&hL[grow][gc0 + 0]   = r0;
      *(float4*)&hL[grow][gc0 + 32]  = r1;
      *(float4*)&hL[grow][gc0 + 64]  = r2;
      *(float4*)&hL[grow][gc0 + 96]  = r3;
      *(float4*)&hL[grow][gc0 + 128] = r4;
      *(float4*)&hL[grow][gc0 + 160] = r5;
      *(float4*)&hL[grow][gc0 + 192] = r6;
      *(float4*)&hL[grow][gc0 + 224] = r7;
    }
    __syncthreads();  // B: hL complete

    // ---- wave 0: recall gate (fp64) + a_rec prefetch ---------------------
    // ---- threads 64..255 (3 waves): h@U k-half, 2b x 2jc -----------------
    float s00 = 0.f, s01 = 0.f, s10 = 0.f, s11 = 0.f;
    if (tid < 64) {
      if (t >= OMEGA) {
        const int gb = tid & 31, kp = tid >> 5;
        double s = 0.0;
        const int k0 = kp * 128;
        for (int k = k0; k < k0 + 128; k += 4) {
          const float4 hv = *(const float4*)&hL[gb][k];
          const float4 uv = *(const float4*)&UrL[k];
          s = fma((double)hv.x, (double)uv.x, s);
          s = fma((double)hv.y, (double)uv.y, s);
          s = fma((double)hv.z, (double)uv.z, s);
          s = fma((double)hv.w, (double)uv.w, s);
        }
        s += __shfl_xor(s, 32, 64);
        double v = (double)PrL[gb] * s;
        v += __shfl_xor(v, 16, 64);
        v += __shfl_xor(v, 8, 64);
        v += __shfl_xor(v, 4, 64);
        v += __shfl_xor(v, 2, 64);
        v += __shfl_xor(v, 1, 64);
        int idx = 0;
        if (tid == 0) {
          const double g = gxt + v;
          const double gate = 1.0 / (1.0 + exp(-g));
          idx = (int)rint((double)t * gate);  // ties-to-even == jnp.round
          if (idx > t - 1) idx = t - 1;
          if (idx < 0) idx = 0;
        }
        idx = __shfl(idx, 0, 64);
        // a_rec = a_cur[idx]: contiguous 1.5KB block in our own AXc region
        const float* __restrict__ src = AXwg + (size_t)idx * G3W;
        float av[6];
#pragma unroll
        for (int j = 0; j < 6; ++j) av[j] = src[lane + j * 64];
#pragma unroll
        for (int j = 0; j < 6; ++j) {
          const int f = lane + j * 64;
          ars[f % JC][f / JC] = av[j];
        }
      }
    } else {
      for (int k = kb; k < kb + 128; k += 4) {
        const float4 u0 = *(const float4*)&ULt[jc0][k];
        const float4 u1 = *(const float4*)&ULt[jc1][k];
        const float4 h0 = *(const float4*)&hL[bA][k];
        const float4 h1 = *(const float4*)&hL[bB][k];
        s00 = fmaf(h0.x, u0.x, s00); s00 = fmaf(h0.y, u0.y, s00);
        s00 = fmaf(h0.z, u0.z, s00); s00 = fmaf(h0.w, u0.w, s00);
        s01 = fmaf(h0.x, u1.x, s01); s01 = fmaf(h0.y, u1.y, s01);
        s01 = fmaf(h0.z, u1.z, s01); s01 = fmaf(h0.w, u1.w, s01);
        s10 = fmaf(h1.x, u0.x, s10); s10 = fmaf(h1.y, u0.y, s10);
        s10 = fmaf(h1.z, u0.z, s10); s10 = fmaf(h1.w, u0.w, s10);
        s11 = fmaf(h1.x, u1.x, s11); s11 = fmaf(h1.y, u1.y, s11);
        s11 = fmaf(h1.z, u1.z, s11); s11 = fmaf(h1.w, u1.w, s11);
      }
      if (khalf == 1) {  // store k-upper partials
        *(float2*)&red1[bA][jc0] = make_float2(s00, s01);
        *(float2*)&red1[bB][jc0] = make_float2(s10, s11);
      }
    }
    __syncthreads();  // C1: red1 + ars complete

    // ---- combine (khalf0 threads): a_cur = red0 + red1 + xw (R1 assoc) ---
    if (tid >= 64 && tid < 160) {
      const float2 rA = *(const float2*)&red1[bA][jc0];
      const float2 rB = *(const float2*)&red1[bB][jc0];
      const float v00 = s00 + rA.x + xwA.x;
      const float v01 = s01 + rA.y + xwA.y;
      const float v10 = s10 + rB.x + xwB.x;
      const float v11 = s11 + rB.y + xwB.y;
      *(float2*)&AXwg[aA] = make_float2(v00, v01);  // bank for future a_rec
      *(float2*)&AXwg[aB] = make_float2(v10, v11);
      acs[jc0][bA] = v00;  acs[jc1][bA] = v01;
      acs[jc0][bB] = v10;  acs[jc1][bB] = v11;
      if (t < OMEGA) {  // use_self: a_rec == a_cur
        ars[jc0][bA] = v00;  ars[jc1][bA] = v01;
        ars[jc0][bB] = v10;  ars[jc1][bB] = v11;
      }
    }
    __syncthreads();  // C2: acs/ars complete

    // ---- owners: gates = P @ [a_cur; a_rec] + bias, LSTM, direct publish -
    if (tid < BSZ * HS) {
      float gi = biasL[ohc];
      float gf = biasL[4 + ohc];
      float gg = biasL[8 + ohc];
#pragma unroll
      for (int b4 = 0; b4 < BSZ; b4 += 4) {
        const float4 pv = *(const float4*)&PL[ob][b4];
        const float4 ai = *(const float4*)&acs[ohc][b4];
        const float4 af = *(const float4*)&acs[4 + ohc][b4];
        const float4 ag = *(const float4*)&acs[8 + ohc][b4];
        gi = fmaf(pv.x, ai.x, gi); gi = fmaf(pv.y, ai.y, gi);
        gi = fmaf(pv.z, ai.z, gi); gi = fmaf(pv.w, ai.w, gi);
        gf = fmaf(pv.x, af.x, gf); gf = fmaf(pv.y, af.y, gf);
        gf = fmaf(pv.z, af.z, gf); gf = fmaf(pv.w, af.w, gf);
        gg = fmaf(pv.x, ag.x, gg); gg = fmaf(pv.y, ag.y, gg);
        gg = fmaf(pv.z, ag.z, gg); gg = fmaf(pv.w, ag.w, gg);
      }
#pragma unroll
      for (int b4 = 0; b4 < BSZ; b4 += 4) {
        const float4 pv = *(const float4*)&PL[ob][BSZ + b4];
        const float4 ai = *(const float4*)&ars[ohc][b4];
        const float4 af = *(const float4*)&ars[4 + ohc][b4];
        const float4 ag = *(const float4*)&ars[8 + ohc][b4];
        gi = fmaf(pv.x, ai.x, gi); gi = fmaf(pv.y, ai.y, gi);
        gi = fmaf(pv.z, ai.z, gi); gi = fmaf(pv.w, ai.w, gi);
        gf = fmaf(pv.x, af.x, gf); gf = fmaf(pv.y, af.y, gf);
        gf = fmaf(pv.z, af.z, gf); gf = fmaf(pv.w, af.w, gf);
        gg = fmaf(pv.x, ag.x, gg); gg = fmaf(pv.y, ag.y, gg);
        gg = fmaf(pv.z, ag.z, gg); gg = fmaf(pv.w, ag.w, gg);
      }
      const float iv = 1.f / (1.f + expf(-gi));
      const float fv = 1.f / (1.f + expf(-gf));
      const float gv = tanhf(gg);
      creg = fmaf(fv, creg, iv * gv);
      const float hv = iv * tanhf(creg);  // o_t = i_t (faithful to source)
      // direct publish: [wg][b][c] flat idx == tid (b=tid>>2, hc=tid&3)
      const uint64_t daddr =
          (uint64_t)(hbank + (size_t)(t + 1) * HSLICE + (size_t)wg * (BSZ * HS)) +
          (uint64_t)tid * 4u;
      asm volatile(
          "global_store_dword %0, %1, off sc0 sc1\n\t"
          "s_waitcnt vmcnt(0)"
          :: "v"(daddr), "v"(hv)
          : "memory");
    }
    __syncthreads();  // D: all publish stores drained
    if (tid == 0) {
      __hip_atomic_fetch_add(&cnt[(wg & 7) * 32], 1u, __ATOMIC_RELAXED,
                             __HIP_MEMORY_SCOPE_AGENT);
    }
  }
}

// ------------------------------ Output -------------------------------------
__global__ void outK(const float* __restrict__ hbank, const float* __restrict__ W_out,
                     const float* __restrict__ b_out, float* __restrict__ out) {
  const int b = threadIdx.x;
  if (b < BSZ) {
    const float* h = hbank + (size_t)T_STEPS * HSLICE;  // [wg][b][c]
    float s = 0.f;
    for (int wg = 0; wg < KWG; ++wg) {
      const float4 hv = *(const float4*)&h[wg * (BSZ * HS) + b * HS];
      const float4 wv = *(const float4*)&W_out[wg * HS];
      s = fmaf(hv.x, wv.x, s); s = fmaf(hv.y, wv.y, s);
      s = fmaf(hv.z, wv.z, s); s = fmaf(hv.w, wv.w, s);
    }
    out[b] = s + b_out[0];
  }
}

// ------------------------------ Launch -------------------------------------
extern "C" void kernel_launch(void* const* d_in, const int* in_sizes, int n_in,
                              void* d_out, int out_size, void* d_ws, size_t ws_size,
                              hipStream_t stream) {
  const float* x      = (const float*)d_in[0];
  const float* W      = (const float*)d_in[1];
  const float* U      = (const float*)d_in[2];
  const float* P      = (const float*)d_in[3];
  const float* B_bias = (const float*)d_in[4];
  const float* W_r    = (const float*)d_in[5];
  const float* P_r    = (const float*)d_in[6];
  const float* U_r    = (const float*)d_in[7];
  const float* W_out  = (const float*)d_in[8];
  const float* b_out  = (const float*)d_in[9];

  char* ws = (char*)d_ws;
  float*    AXc   = (float*)ws;
  float*    hbank = (float*)(ws + AXC_BYTES);
  double*   gx    = (double*)(ws + AXC_BYTES + HB_BYTES);
  unsigned* cnt   = (unsigned*)(ws + AXC_BYTES + HB_BYTES + GX_BYTES);

  hipMemsetAsync(hbank, 0, (size_t)HSLICE * sizeof(float), stream);  // h0 = 0
  hipMemsetAsync(cnt, 0, 1024, stream);                              // counters

  phaseA<<<T_STEPS, 256, 0, stream>>>(x, W, W_r, P_r, AXc, gx);
  phaseB<<<KWG, 256, 0, stream>>>(U, P, B_bias, P_r, U_r, AXc, hbank, gx, cnt);
  outK<<<1, 64, 0, stream>>>(hbank, W_out, b_out, (float*)d_out);
}